// Round 1
// baseline (65076.587 us; speedup 1.0000x reference)
//
#include <hip/hip_runtime.h>

// ---------------------------------------------------------------------------
// Hierarchical GRU predictor, fp32 baseline.
// B=64, T=256, D_IN=256, H=512, A=128, DEPTH=4.
//
// Decomposition:
//  - pack:   Wc = [W | W_action_1] (512x1664), Uc = [Uz|Ur|Ua] (512x1152), bc
//  - emb:    xe = x @ W_emb + b_emb  -> written into pix[:,0,:,:]
//  - per level d (4):
//      per chunk of 64 timesteps (4): XWA = x_d @ Wc + bc  (4096x1664, K=512)
//      per t: gemmA: G1 = h_prev @ Uc (64x1152)
//             stepB: pol/act logic, r, (r*h)@Uh, z, h_cand, gated h update,
//                    all output writes.
//  - h of level d written straight into pix[:,d+1] (= next level's input).
// Sequential chain: 1024 steps x 2 kernels -> launch/latency bound baseline.
// ---------------------------------------------------------------------------

#define Bn   64
#define Tn   256
#define DIN  256
#define Hn   512
#define An   128
#define DEP  4
#define N3   1536   // 3*H
#define NC   1664   // N3 + A   (Wc width)
#define NU   1152   // 2*H + A  (Uc width)

__device__ __forceinline__ float hsigf(float v) {
    return fminf(fmaxf(0.2f * v + 0.5f, 0.f), 1.f);
}

// ---------------------------------------------------------------- pack / init
__global__ __launch_bounds__(256) void pack_w_k(const float* __restrict__ W,
                                                const float* __restrict__ Wa1,
                                                float* __restrict__ Wc) {
    int idx = blockIdx.x * 256 + threadIdx.x;
    if (idx >= Hn * NC) return;
    int k = idx / NC, c = idx % NC;
    Wc[idx] = (c < N3) ? W[(size_t)k * N3 + c] : Wa1[(size_t)k * An + (c - N3)];
}

__global__ __launch_bounds__(256) void pack_u_k(const float* __restrict__ U,
                                                const float* __restrict__ Ua1,
                                                float* __restrict__ Uc) {
    int idx = blockIdx.x * 256 + threadIdx.x;
    if (idx >= Hn * NU) return;
    int k = idx / NU, c = idx % NU;
    Uc[idx] = (c < 1024) ? U[(size_t)k * N3 + c] : Ua1[(size_t)k * An + (c - 1024)];
}

__global__ __launch_bounds__(256) void init_misc_k(const float* __restrict__ bb,
                                                   const float* __restrict__ ba1,
                                                   float* __restrict__ bc,
                                                   const float* __restrict__ mask,
                                                   float* __restrict__ seos,
                                                   float* __restrict__ dmh0,
                                                   float* __restrict__ o_pih) {
    int idx = blockIdx.x * 256 + threadIdx.x;
    if (idx < NC) bc[idx] = (idx < N3) ? bb[idx] : ba1[idx - N3];
    if (idx < Tn * Bn) {
        int t = idx / Bn, b = idx % Bn;
        float m0 = mask[(size_t)b * Tn + t];
        dmh0[idx] = m0;                       // dm_hist[0][t][b]
        float s = 0.f;                        // seos[t] = eos[t-1]
        if (t > 0) s = mask[(size_t)b * Tn + (t - 1)] * (1.f - m0);
        seos[idx] = s;
    }
    if (idx < Bn * DEP * Hn) {                // pih[:, :, 0, :] = 0
        int b = idx / (DEP * Hn);
        int r = idx % (DEP * Hn);
        int d = r / Hn, h = r % Hn;
        o_pih[(((size_t)b * DEP + d) * Tn + 0) * Hn + h] = 0.f;
    }
}

__global__ __launch_bounds__(256) void zero_k(float* __restrict__ p, int n) {
    int i = blockIdx.x * 256 + threadIdx.x;
    if (i < n) p[i] = 0.f;
}

// ------------------------------------------------------------ generic 64x64 GEMM
// C[qm-tile, qn-tile] = A @ B + bias.  Tile rows share one "t": row m of tile
// qm sits at A + aBase0 + qm*aStep + m*aStride (same for C).
__global__ __launch_bounds__(256) void gemm64_k(
    const float* __restrict__ Am, long aBase0, long aStep, long aStride,
    const float* __restrict__ Bm, int ldb, const float* __restrict__ bias,
    float* __restrict__ Cm, long cBase0, long cStep, long cStride, int K) {
    const int qm = blockIdx.x, qn = blockIdx.y;
    const long aBase = aBase0 + (long)qm * aStep;
    const long cBase = cBase0 + (long)qm * cStep;
    const int n0 = qn * 64;
    __shared__ float As[64][65];   // As[k][m], pitch 65 -> conflict-free scalar reads
    __shared__ float Bs[64][68];   // Bs[k][n], pitch 68 -> aligned float4 reads
    const int tid = threadIdx.x;
    const int tx = tid & 15, ty = tid >> 4;
    float acc[4][4] = {};
    for (int k0 = 0; k0 < K; k0 += 64) {
#pragma unroll
        for (int fi = 0; fi < 4; ++fi) {       // A tile 64x64
            const int f = fi * 256 + tid;
            const int mm = f >> 4;
            const int k4 = (f & 15) << 2;
            const float4 v = *(const float4*)(Am + aBase + (long)mm * aStride + k0 + k4);
            As[k4 + 0][mm] = v.x; As[k4 + 1][mm] = v.y;
            As[k4 + 2][mm] = v.z; As[k4 + 3][mm] = v.w;
        }
#pragma unroll
        for (int fi = 0; fi < 4; ++fi) {       // B tile 64x64
            const int f = fi * 256 + tid;
            const int k = f >> 4;
            const int n4 = (f & 15) << 2;
            *(float4*)&Bs[k][n4] = *(const float4*)(Bm + (long)(k0 + k) * ldb + n0 + n4);
        }
        __syncthreads();
#pragma unroll 16
        for (int k = 0; k < 64; ++k) {
            const float a0 = As[k][ty * 4 + 0];
            const float a1 = As[k][ty * 4 + 1];
            const float a2 = As[k][ty * 4 + 2];
            const float a3 = As[k][ty * 4 + 3];
            const float4 bv = *(const float4*)&Bs[k][tx * 4];
            acc[0][0] = fmaf(a0, bv.x, acc[0][0]); acc[0][1] = fmaf(a0, bv.y, acc[0][1]);
            acc[0][2] = fmaf(a0, bv.z, acc[0][2]); acc[0][3] = fmaf(a0, bv.w, acc[0][3]);
            acc[1][0] = fmaf(a1, bv.x, acc[1][0]); acc[1][1] = fmaf(a1, bv.y, acc[1][1]);
            acc[1][2] = fmaf(a1, bv.z, acc[1][2]); acc[1][3] = fmaf(a1, bv.w, acc[1][3]);
            acc[2][0] = fmaf(a2, bv.x, acc[2][0]); acc[2][1] = fmaf(a2, bv.y, acc[2][1]);
            acc[2][2] = fmaf(a2, bv.z, acc[2][2]); acc[2][3] = fmaf(a2, bv.w, acc[2][3]);
            acc[3][0] = fmaf(a3, bv.x, acc[3][0]); acc[3][1] = fmaf(a3, bv.y, acc[3][1]);
            acc[3][2] = fmaf(a3, bv.z, acc[3][2]); acc[3][3] = fmaf(a3, bv.w, acc[3][3]);
        }
        __syncthreads();
    }
#pragma unroll
    for (int i = 0; i < 4; ++i) {
        const int mm = ty * 4 + i;
        float* cp = Cm + cBase + (long)mm * cStride + n0 + tx * 4;
#pragma unroll
        for (int j = 0; j < 4; ++j) {
            float v = acc[i][j];
            if (bias) v += bias[n0 + tx * 4 + j];
            cp[j] = v;
        }
    }
}

// ---------------------------------------------------- per-step kernel A (G1)
// G1 = h_prev @ Uc : (64 x 512) @ (512 x 1152). Tiles 16(M) x 64(N), grid (4,18).
__global__ __launch_bounds__(256) void gemmA_k(const float* __restrict__ hprev,
                                               const float* __restrict__ Uc,
                                               float* __restrict__ G1) {
    const int qm = blockIdx.x;
    const int n0 = blockIdx.y * 64;
    __shared__ float As[64][17];   // As[k][m], 16 rows
    __shared__ float Bs[64][68];
    const int tid = threadIdx.x;
    const int m = tid >> 4, nn = (tid & 15) << 2;
    float acc0 = 0.f, acc1 = 0.f, acc2 = 0.f, acc3 = 0.f;
    for (int k0 = 0; k0 < Hn; k0 += 64) {
        {   // A tile 16x64: one float4 per thread
            const int am = tid >> 4;
            const int k4 = (tid & 15) << 2;
            const float4 v = *(const float4*)(hprev + (size_t)(qm * 16 + am) * Hn + k0 + k4);
            As[k4 + 0][am] = v.x; As[k4 + 1][am] = v.y;
            As[k4 + 2][am] = v.z; As[k4 + 3][am] = v.w;
        }
#pragma unroll
        for (int fi = 0; fi < 4; ++fi) {   // B tile 64x64
            const int f = fi * 256 + tid;
            const int k = f >> 4;
            const int n4 = (f & 15) << 2;
            *(float4*)&Bs[k][n4] = *(const float4*)(Uc + (size_t)(k0 + k) * NU + n0 + n4);
        }
        __syncthreads();
#pragma unroll 16
        for (int k = 0; k < 64; ++k) {
            const float a = As[k][m];
            const float4 bv = *(const float4*)&Bs[k][nn];
            acc0 = fmaf(a, bv.x, acc0);
            acc1 = fmaf(a, bv.y, acc1);
            acc2 = fmaf(a, bv.z, acc2);
            acc3 = fmaf(a, bv.w, acc3);
        }
        __syncthreads();
    }
    float* cp = G1 + (size_t)(qm * 16 + m) * NU + n0 + nn;
    cp[0] = acc0; cp[1] = acc1; cp[2] = acc2; cp[3] = acc3;
}

// ---------------------------------------------------- per-step kernel B (rest)
// grid (4, 8): qm = 16-batch-row tile, qn = 64-col tile of H.
__global__ __launch_bounds__(256) void stepB_k(
    const float* __restrict__ XWA, const float* __restrict__ G1,
    const float* __restrict__ Umat, const float* __restrict__ W2,
    const float* __restrict__ b2, const float* __restrict__ hprev,
    float* __restrict__ hnext, const float* __restrict__ seos,
    float* __restrict__ dmh, float* __restrict__ acth,
    float* __restrict__ o_act, float* __restrict__ o_ac, float* __restrict__ o_pol,
    float* __restrict__ o_pix, float* __restrict__ o_pih, float* __restrict__ o_out,
    int t, int d, int llm) {
    const int qm = blockIdx.x, qn = blockIdx.y;
    const int n0 = qn * 64;
    const int tid = threadIdx.x;
    const int tt = t & 63;
    __shared__ float rh_s[64][17];   // rh_s[k][b16], pitch 17 (conflict-free)
    __shared__ float uh_s[64][68];
    __shared__ float s_both[16], s_ho[16], s_xo[16], s_dmp[16];

    if (tid < 16) {   // per-batch scalar logic (act / gating)
        const int b = qm * 16 + tid;
        const float dmp_tm1 = (t == 0) ? 1.f : dmh[(size_t)d * Tn * Bn + (t - 1) * Bn + b];
        const float dmp     = dmh[(size_t)d * Tn * Bn + t * Bn + b];
        const float ap      = (d == 0) ? 0.f : o_act[(size_t)b * DEP * Tn + (d - 1) * Tn + t];
        const float e_tm1   = seos[t * Bn + b];
        const float a_tm1   = (t == 0) ? 0.f : acth[(t - 1) * Bn + b];
        const float dmc_tm1 = (t == 0) ? 0.f : dmh[(size_t)(d + 1) * Tn * Bn + (t - 1) * Bn + b];
        float p0 = b2[0], p1 = b2[1];
        const float* xa = XWA + ((size_t)tt * Bn + b) * NC + N3;
        const float* ga = G1 + (size_t)b * NU + 1024;
        for (int i = 0; i < An; ++i) {
            float ph = fmaxf(xa[i] + ga[i], 0.f);
            p0 = fmaf(ph, W2[i * 2 + 0], p0);
            p1 = fmaf(ph, W2[i * 2 + 1], p1);
        }
        p0 = expf(p0); p1 = expf(p1);
        float act = (p0 >= p1) ? 1.f : 0.f;
        if (ap > 0.f) act = 1.f;
        if (llm) act = 1.f;
        if (e_tm1 > 0.f) act = 0.f;
        const float lf = llm ? 1.f : 0.f;
        const float acalc = dmp_tm1 * (1.f - lf) * (1.f - e_tm1) * (1.f - ap);
        const float both   = (1.f - ap) * dmp * act * dmc_tm1;
        const float h_only = dmc_tm1 * act * (ap + (1.f - ap) * (1.f - dmp));
        const float x_only = dmp * (1.f - ap) * (1.f - act + act * (1.f - dmc_tm1));
        float dm_new = both + x_only + h_only;
        const float act_out = (dmp_tm1 > 0.f) ? act : a_tm1;
        dm_new = dmp * dm_new;
        s_both[tid] = both; s_ho[tid] = h_only; s_xo[tid] = x_only; s_dmp[tid] = dmp;
        if (qn == 0) {
            acth[t * Bn + b] = act_out;
            dmh[(size_t)(d + 1) * Tn * Bn + t * Bn + b] = dm_new;
            o_ac[(size_t)b * DEP * Tn + d * Tn + t] = acalc;
            o_pol[((size_t)b * DEP * Tn + d * Tn + t) * 2 + 0] = p0;
            o_pol[((size_t)b * DEP * Tn + d * Tn + t) * 2 + 1] = p1;
            if (t > 0) o_act[(size_t)b * DEP * Tn + d * Tn + (t - 1)] = act_out;  // sa shift
            if (t == Tn - 1) o_act[(size_t)b * DEP * Tn + d * Tn + (Tn - 1)] = 0.f;
        }
    }
    __syncthreads();

    // GEMM2: acc = (r*h_prev) @ Uh[:, n0:n0+64], 16 batch rows of this tile.
    float acc0 = 0.f, acc1 = 0.f, acc2 = 0.f, acc3 = 0.f;
    const int m = tid >> 4, nn = (tid & 15) << 2;
    for (int kc = 0; kc < 8; ++kc) {
        const int kb = kc * 64;
#pragma unroll
        for (int i2 = 0; i2 < 4; ++i2) {   // rh chunk 16x64
            const int e = i2 * 256 + tid;
            const int b16 = e >> 6, kk = e & 63;
            const int b = qm * 16 + b16;
            const int k = kb + kk;
            const float g = XWA[((size_t)tt * Bn + b) * NC + Hn + k] + G1[(size_t)b * NU + Hn + k];
            const float r = hsigf(g);
            rh_s[kk][b16] = r * hprev[(size_t)b * Hn + k];
        }
#pragma unroll
        for (int i2 = 0; i2 < 4; ++i2) {   // Uh chunk 64x64
            const int f = i2 * 256 + tid;
            const int k = f >> 4, j4 = (f & 15) << 2;
            *(float4*)&uh_s[k][j4] =
                *(const float4*)(Umat + (size_t)(kb + k) * N3 + 1024 + n0 + j4);
        }
        __syncthreads();
#pragma unroll 16
        for (int k = 0; k < 64; ++k) {
            const float a = rh_s[k][m];
            const float4 bv = *(const float4*)&uh_s[k][nn];
            acc0 = fmaf(a, bv.x, acc0);
            acc1 = fmaf(a, bv.y, acc1);
            acc2 = fmaf(a, bv.z, acc2);
            acc3 = fmaf(a, bv.w, acc3);
        }
        __syncthreads();
    }

    // epilogue: z, h_cand, gated select, writes.
    const int b = qm * 16 + m;
    const float both = s_both[m], h_only = s_ho[m], x_only = s_xo[m], dmp = s_dmp[m];
    const float accs[4] = {acc0, acc1, acc2, acc3};
#pragma unroll
    for (int jj = 0; jj < 4; ++jj) {
        const int j = n0 + nn + jj;
        const size_t xrow = ((size_t)tt * Bn + b) * NC;
        const float z = hsigf(XWA[xrow + j] + G1[(size_t)b * NU + j]);
        const float hp = hprev[(size_t)b * Hn + j];
        const float th = tanhf(XWA[xrow + 1024 + j] + accs[jj]);
        const float hc = z * hp + (1.f - z) * th;
        const float xt = o_pix[(((size_t)b * DEP + d) * Tn + t) * Hn + j];
        float hv = (both > 0.f) ? hc : 0.f;
        if (h_only > 0.f) hv = hp;
        if (x_only > 0.f) hv = xt;
        if (!(dmp > 0.f)) hv = hp;
        hnext[(size_t)b * Hn + j] = hv;
        if (d < DEP - 1) o_pix[(((size_t)b * DEP + d + 1) * Tn + t) * Hn + j] = hv;
        if (t > 0)       o_pih[(((size_t)b * DEP + d) * Tn + t) * Hn + j] = hv;   // pih[t]=h[t], t>=1
        if (d == DEP - 1 && t == Tn - 1) o_out[(size_t)b * Hn + j] = hv;
    }
}

// ---------------------------------------------------------------------------
extern "C" void kernel_launch(void* const* d_in, const int* in_sizes, int n_in,
                              void* d_out, int out_size, void* d_ws, size_t ws_size,
                              hipStream_t stream) {
    const float* x     = (const float*)d_in[0];
    const float* mask  = (const float*)d_in[1];
    // d_in[2] = bucket_size (==T, compile-time constant here)
    const float* W_emb = (const float*)d_in[3];
    const float* b_emb = (const float*)d_in[4];
    const float* W     = (const float*)d_in[5];
    const float* U     = (const float*)d_in[6];
    const float* bb    = (const float*)d_in[7];
    const float* Wa1   = (const float*)d_in[8];
    const float* Ua1   = (const float*)d_in[9];
    const float* ba1   = (const float*)d_in[10];
    const float* W2    = (const float*)d_in[11];
    const float* b2    = (const float*)d_in[12];

    float* out = (float*)d_out;
    float* o_out = out;                                   // (B,H)
    float* o_act = out + (size_t)Bn * Hn;                 // (B,D,T)
    float* o_ac  = o_act + (size_t)Bn * DEP * Tn;         // (B,D,T)
    float* o_pix = o_ac + (size_t)Bn * DEP * Tn;          // (B,D,T,H)
    float* o_pih = o_pix + (size_t)Bn * DEP * Tn * Hn;    // (B,D,T,H)
    float* o_pol = o_pih + (size_t)Bn * DEP * Tn * Hn;    // (B,D,T,2)

    float* ws   = (float*)d_ws;
    float* seos = ws;                      // T*B
    float* dmh  = seos + Tn * Bn;          // (DEP+1)*T*B
    float* acth = dmh + (DEP + 1) * Tn * Bn;   // T*B
    float* hbuf = acth + Tn * Bn;          // 2*B*H
    float* G1   = hbuf + 2 * Bn * Hn;      // B*NU
    float* Wc   = G1 + Bn * NU;            // H*NC
    float* bc   = Wc + (size_t)Hn * NC;    // NC
    float* Uc   = bc + NC;                 // H*NU
    float* XWA  = Uc + (size_t)Hn * NU;    // 64*B*NC (one 64-step chunk)

    pack_w_k<<<(Hn * NC + 255) / 256, 256, 0, stream>>>(W, Wa1, Wc);
    pack_u_k<<<(Hn * NU + 255) / 256, 256, 0, stream>>>(U, Ua1, Uc);
    init_misc_k<<<(Bn * DEP * Hn + 255) / 256, 256, 0, stream>>>(bb, ba1, bc, mask, seos,
                                                                 dmh, o_pih);

    // emb: xe[t,b,:] = x[b,t,:] @ W_emb + b_emb  -> pix[:,0]
    gemm64_k<<<dim3(Tn, Hn / 64), 256, 0, stream>>>(
        x, 0L, (long)DIN, (long)Tn * DIN, W_emb, Hn, b_emb,
        o_pix, 0L, (long)Hn, (long)DEP * Tn * Hn, DIN);

    for (int d = 0; d < DEP; ++d) {
        zero_k<<<(Bn * Hn + 255) / 256, 256, 0, stream>>>(hbuf, Bn * Hn);
        for (int c = 0; c < 4; ++c) {
            // XWA = x_d[chunk] @ Wc + bc
            gemm64_k<<<dim3(64, NC / 64), 256, 0, stream>>>(
                o_pix, (long)(d * Tn + c * 64) * Hn, (long)Hn, (long)DEP * Tn * Hn,
                Wc, NC, bc, XWA, 0L, (long)Bn * NC, (long)NC, Hn);
            for (int tt = 0; tt < 64; ++tt) {
                const int t = c * 64 + tt;
                const float* hprev = hbuf + (size_t)(t & 1) * Bn * Hn;
                float* hnext = hbuf + (size_t)((t + 1) & 1) * Bn * Hn;
                gemmA_k<<<dim3(4, NU / 64), 256, 0, stream>>>(hprev, Uc, G1);
                stepB_k<<<dim3(4, Hn / 64), 256, 0, stream>>>(
                    XWA, G1, U, W2, b2, hprev, hnext, seos, dmh, acth,
                    o_act, o_ac, o_pol, o_pix, o_pih, o_out,
                    t, d, (d == DEP - 1) ? 1 : 0);
            }
        }
    }
}

// Round 3
// 19512.569 us; speedup vs baseline: 3.3351x; 3.3351x over previous
//
#include <hip/hip_runtime.h>

// ---------------------------------------------------------------------------
// Hierarchical GRU predictor — persistent per-batch scan, column-split x4.
// B=64, T=256, D_IN=256, H=512, A=128, DEPTH=4.
//
//  - XWA = x_d @ [W|W_action_1] hoisted per 64-step chunk (full-chip GEMM).
//  - scan_chunk_k: grid (64 batches, 4 slices). Each step:
//      phase1: wg s computes G1 cols [288s,288s+288) of h@Uc (Uc=[Uz|Ur|Ua]);
//              wg3 (owns all A-cols) computes pol/act/dm gates.
//      sync1 (per-batch flag)
//      phase2: all wgs build rh=hsig(xr+G1r)*h in LDS, compute 128-col slice
//              of (rh)@Uh, gated h update, all output writes.
//      sync2.
//    Exchanged data (hbuf/G1buf/gatebuf) uses relaxed-agent atomics (bypass
//    L1/L2 to the coherent point) so weight streams stay L2-cached.
//    Sync flags: RELAXED add + RELAXED spin. Safe because (a) all exchanged
//    data moves via coherent-point atomics (never cached locally), and
//    (b) __syncthreads() drains vmcnt(0) for ALL threads' stores before
//    thread 0 issues the flag add. Acquire spins would emit buffer_inv sc1
//    (L2 invalidate) per poll on gfx950 and evict the weight cache.
// ---------------------------------------------------------------------------

#define Bn   64
#define Tn   256
#define DIN  256
#define Hn   512
#define An   128
#define DEP  4
#define N3   1536
#define NC   1664   // N3 + A
#define NU   1152   // 2*H + A
#define THREADS 320

__device__ __forceinline__ float hsigf(float v) {
    return fminf(fmaxf(0.2f * v + 0.5f, 0.f), 1.f);
}
__device__ __forceinline__ float aloadf(const float* p) {
    return __hip_atomic_load(p, __ATOMIC_RELAXED, __HIP_MEMORY_SCOPE_AGENT);
}
__device__ __forceinline__ void astoref(float* p, float v) {
    __hip_atomic_store(p, v, __ATOMIC_RELAXED, __HIP_MEMORY_SCOPE_AGENT);
}

// ---------------------------------------------------------------- pack / init
__global__ __launch_bounds__(256) void pack_w_k(const float* __restrict__ W,
                                                const float* __restrict__ Wa1,
                                                float* __restrict__ Wc) {
    int idx = blockIdx.x * 256 + threadIdx.x;
    if (idx >= Hn * NC) return;
    int k = idx / NC, c = idx % NC;
    Wc[idx] = (c < N3) ? W[(size_t)k * N3 + c] : Wa1[(size_t)k * An + (c - N3)];
}

__global__ __launch_bounds__(256) void pack_u_k(const float* __restrict__ U,
                                                const float* __restrict__ Ua1,
                                                float* __restrict__ Uc) {
    int idx = blockIdx.x * 256 + threadIdx.x;
    if (idx >= Hn * NU) return;
    int k = idx / NU, c = idx % NU;
    Uc[idx] = (c < 1024) ? U[(size_t)k * N3 + c] : Ua1[(size_t)k * An + (c - 1024)];
}

__global__ __launch_bounds__(256) void init_misc_k(const float* __restrict__ bb,
                                                   const float* __restrict__ ba1,
                                                   float* __restrict__ bc,
                                                   const float* __restrict__ mask,
                                                   float* __restrict__ seos,
                                                   float* __restrict__ dmh0,
                                                   float* __restrict__ o_pih,
                                                   unsigned int* __restrict__ flags) {
    int idx = blockIdx.x * 256 + threadIdx.x;
    if (idx < NC) bc[idx] = (idx < N3) ? bb[idx] : ba1[idx - N3];
    if (idx < 128) flags[idx] = 0u;
    if (idx < Tn * Bn) {
        int t = idx / Bn, b = idx % Bn;
        float m0 = mask[(size_t)b * Tn + t];
        dmh0[idx] = m0;                       // dm_hist[0][t][b]
        float s = 0.f;                        // seos[t] = eos[t-1]
        if (t > 0) s = mask[(size_t)b * Tn + (t - 1)] * (1.f - m0);
        seos[idx] = s;
    }
    if (idx < Bn * DEP * Hn) {                // pih[:, :, 0, :] = 0
        int b = idx / (DEP * Hn);
        int r = idx % (DEP * Hn);
        int d = r / Hn, h = r % Hn;
        o_pih[(((size_t)b * DEP + d) * Tn + 0) * Hn + h] = 0.f;
    }
}

// ------------------------------------------------------------ 64x64 tile GEMM
__global__ __launch_bounds__(256) void gemm64_k(
    const float* __restrict__ Am, long aBase0, long aStep, long aStride,
    const float* __restrict__ Bm, int ldb, const float* __restrict__ bias,
    float* __restrict__ Cm, long cBase0, long cStep, long cStride, int K) {
    const int qm = blockIdx.x, qn = blockIdx.y;
    const long aBase = aBase0 + (long)qm * aStep;
    const long cBase = cBase0 + (long)qm * cStep;
    const int n0 = qn * 64;
    __shared__ float As[64][65];
    __shared__ float Bs[64][68];
    const int tid = threadIdx.x;
    const int tx = tid & 15, ty = tid >> 4;
    float acc[4][4] = {};
    for (int k0 = 0; k0 < K; k0 += 64) {
#pragma unroll
        for (int fi = 0; fi < 4; ++fi) {
            const int f = fi * 256 + tid;
            const int mm = f >> 4;
            const int k4 = (f & 15) << 2;
            const float4 v = *(const float4*)(Am + aBase + (long)mm * aStride + k0 + k4);
            As[k4 + 0][mm] = v.x; As[k4 + 1][mm] = v.y;
            As[k4 + 2][mm] = v.z; As[k4 + 3][mm] = v.w;
        }
#pragma unroll
        for (int fi = 0; fi < 4; ++fi) {
            const int f = fi * 256 + tid;
            const int k = f >> 4;
            const int n4 = (f & 15) << 2;
            *(float4*)&Bs[k][n4] = *(const float4*)(Bm + (long)(k0 + k) * ldb + n0 + n4);
        }
        __syncthreads();
#pragma unroll 16
        for (int k = 0; k < 64; ++k) {
            const float a0 = As[k][ty * 4 + 0];
            const float a1 = As[k][ty * 4 + 1];
            const float a2 = As[k][ty * 4 + 2];
            const float a3 = As[k][ty * 4 + 3];
            const float4 bv = *(const float4*)&Bs[k][tx * 4];
            acc[0][0] = fmaf(a0, bv.x, acc[0][0]); acc[0][1] = fmaf(a0, bv.y, acc[0][1]);
            acc[0][2] = fmaf(a0, bv.z, acc[0][2]); acc[0][3] = fmaf(a0, bv.w, acc[0][3]);
            acc[1][0] = fmaf(a1, bv.x, acc[1][0]); acc[1][1] = fmaf(a1, bv.y, acc[1][1]);
            acc[1][2] = fmaf(a1, bv.z, acc[1][2]); acc[1][3] = fmaf(a1, bv.w, acc[1][3]);
            acc[2][0] = fmaf(a2, bv.x, acc[2][0]); acc[2][1] = fmaf(a2, bv.y, acc[2][1]);
            acc[2][2] = fmaf(a2, bv.z, acc[2][2]); acc[2][3] = fmaf(a2, bv.w, acc[2][3]);
            acc[3][0] = fmaf(a3, bv.x, acc[3][0]); acc[3][1] = fmaf(a3, bv.y, acc[3][1]);
            acc[3][2] = fmaf(a3, bv.z, acc[3][2]); acc[3][3] = fmaf(a3, bv.w, acc[3][3]);
        }
        __syncthreads();
    }
#pragma unroll
    for (int i = 0; i < 4; ++i) {
        const int mm = ty * 4 + i;
        float* cp = Cm + cBase + (long)mm * cStride + n0 + tx * 4;
#pragma unroll
        for (int j = 0; j < 4; ++j) {
            float v = acc[i][j];
            if (bias) v += bias[n0 + tx * 4 + j];
            cp[j] = v;
        }
    }
}

// ---------------------------------------------------- persistent scan (chunk)
__global__ __launch_bounds__(THREADS) void scan_chunk_k(
    const float* __restrict__ XWA, const float* __restrict__ Uc,
    const float* __restrict__ Umat, const float* __restrict__ W2,
    const float* __restrict__ b2,
    float* __restrict__ hbuf,            // [2][B][H]
    float* __restrict__ G1buf,           // [B][NU]
    float* __restrict__ gatebuf,         // [B][8]
    unsigned int* __restrict__ flags,    // [2][64]
    const float* __restrict__ seos, float* __restrict__ dmh,
    float* __restrict__ acth,
    float* __restrict__ o_act, float* __restrict__ o_ac, float* __restrict__ o_pol,
    float* __restrict__ o_pix, float* __restrict__ o_pih, float* __restrict__ o_out,
    int d, int c) {
    const int b = blockIdx.x;
    const int s = blockIdx.y;
    const int tid = threadIdx.x;
    const int llm = (d == DEP - 1) ? 1 : 0;

    __shared__ float h_s[Hn];
    __shared__ float rh_s[Hn];
    __shared__ float red_s[4][288];
    __shared__ float ph_s[An];
    __shared__ float gate_s[4];

    unsigned int* arr1 = flags;
    unsigned int* arr2 = flags + 64;

    // wg3/thread0 persistent scalars (restored at chunk entry)
    float a_prev = 0.f, dmc_prev = 0.f;
    if (s == 3 && tid == 0 && c > 0) {
        const int t0 = c * 64;
        a_prev   = acth[(t0 - 1) * Bn + b];
        dmc_prev = dmh[(size_t)(d + 1) * Tn * Bn + (t0 - 1) * Bn + b];
    }

    for (int tt = 0; tt < 64; ++tt) {
        const int t = c * 64 + tt;
        const int g = d * Tn + t;            // global step index (monotone)
        const int par = g & 1;
        const unsigned int tgt = 4u * (unsigned)(g + 1);
        const float* xrow = XWA + ((size_t)tt * Bn + b) * NC;

        // early scalar prefetch for the gate logic (hidden under dot loop)
        float dmp_tm1 = 1.f, dmp = 0.f, ap = 0.f, e_tm1 = 0.f;
        if (s == 3 && tid == 0) {
            dmp = dmh[(size_t)d * Tn * Bn + t * Bn + b];
            if (t > 0) dmp_tm1 = dmh[(size_t)d * Tn * Bn + (t - 1) * Bn + b];
            if (d > 0) ap = o_act[(size_t)b * DEP * Tn + (d - 1) * Tn + t];
            e_tm1 = seos[t * Bn + b];
        }

        // ---- load hprev into LDS (atomic: written by other wgs last step)
        for (int k = tid; k < Hn; k += THREADS)
            h_s[k] = (t == 0) ? 0.f : aloadf(&hbuf[((size_t)par * Bn + b) * Hn + k]);
        __syncthreads();

        // ---- phase1: G1 slice = h @ Uc[:, 288s .. 288s+288)
        if (tid < 288) {
            const int gq = tid % 72, kq = tid / 72;
            const int j0 = s * 288 + 4 * gq;
            const float* wp = Uc + (size_t)(kq * 128) * NU + j0;
            float4 acc = {0.f, 0.f, 0.f, 0.f};
#pragma unroll 8
            for (int k = 0; k < 128; ++k) {
                const float4 w = *(const float4*)(wp + (size_t)k * NU);
                const float hk = h_s[kq * 128 + k];
                acc.x = fmaf(w.x, hk, acc.x); acc.y = fmaf(w.y, hk, acc.y);
                acc.z = fmaf(w.z, hk, acc.z); acc.w = fmaf(w.w, hk, acc.w);
            }
            *(float4*)&red_s[kq][4 * gq] = acc;
        }
        __syncthreads();
        float myG1 = 0.f;
        if (tid < 288) {
            myG1 = red_s[0][tid] + red_s[1][tid] + red_s[2][tid] + red_s[3][tid];
            astoref(&G1buf[(size_t)b * NU + s * 288 + tid], myG1);
        }
        if (s == 3 && tid >= 160 && tid < 288) {   // A-cols 1024..1152 local
            const int i = tid - 160;
            ph_s[i] = fmaxf(xrow[N3 + i] + myG1, 0.f);
        }
        __syncthreads();

        // ---- wg3: pol / act / dm gates
        if (s == 3 && tid < 64) {
            float p0p = ph_s[tid] * W2[2 * tid]     + ph_s[tid + 64] * W2[2 * (tid + 64)];
            float p1p = ph_s[tid] * W2[2 * tid + 1] + ph_s[tid + 64] * W2[2 * (tid + 64) + 1];
            for (int off = 32; off; off >>= 1) {
                p0p += __shfl_down(p0p, off);
                p1p += __shfl_down(p1p, off);
            }
            if (tid == 0) {
                const float p0 = expf(b2[0] + p0p), p1 = expf(b2[1] + p1p);
                const float a_tm1   = (t == 0) ? 0.f : a_prev;
                const float dmc_tm1 = (t == 0) ? 0.f : dmc_prev;
                float act = (p0 >= p1) ? 1.f : 0.f;
                if (ap > 0.f) act = 1.f;
                if (llm) act = 1.f;
                if (e_tm1 > 0.f) act = 0.f;
                const float lf = llm ? 1.f : 0.f;
                const float acalc  = dmp_tm1 * (1.f - lf) * (1.f - e_tm1) * (1.f - ap);
                const float both   = (1.f - ap) * dmp * act * dmc_tm1;
                const float h_only = dmc_tm1 * act * (ap + (1.f - ap) * (1.f - dmp));
                const float x_only = dmp * (1.f - ap) * (1.f - act + act * (1.f - dmc_tm1));
                const float dm_new = dmp * (both + x_only + h_only);
                const float act_out = (dmp_tm1 > 0.f) ? act : a_tm1;
                astoref(&gatebuf[b * 8 + 0], both);
                astoref(&gatebuf[b * 8 + 1], h_only);
                astoref(&gatebuf[b * 8 + 2], x_only);
                astoref(&gatebuf[b * 8 + 3], dmp);
                dmh[(size_t)(d + 1) * Tn * Bn + t * Bn + b] = dm_new;
                o_ac[(size_t)b * DEP * Tn + d * Tn + t] = acalc;
                o_pol[((size_t)b * DEP * Tn + d * Tn + t) * 2 + 0] = p0;
                o_pol[((size_t)b * DEP * Tn + d * Tn + t) * 2 + 1] = p1;
                acth[t * Bn + b] = act_out;
                if (t > 0) o_act[(size_t)b * DEP * Tn + d * Tn + (t - 1)] = act_out;
                if (t == Tn - 1) o_act[(size_t)b * DEP * Tn + d * Tn + (Tn - 1)] = 0.f;
                a_prev = act_out; dmc_prev = dm_new;
            }
        }

        // ---- sync1: all 4 slices' G1 (+gates) at coherence point.
        // __syncthreads drains vmcnt(0) for all threads before the add.
        __syncthreads();
        if (tid == 0) {
            __hip_atomic_fetch_add(&arr1[b], 1u, __ATOMIC_RELAXED, __HIP_MEMORY_SCOPE_AGENT);
            while (__hip_atomic_load(&arr1[b], __ATOMIC_RELAXED, __HIP_MEMORY_SCOPE_AGENT) < tgt)
                __builtin_amdgcn_s_sleep(1);
        }
        __syncthreads();

        // ---- phase2: rh into LDS, then (rh)@Uh slice + gated update
        if (tid < 4) gate_s[tid] = aloadf(&gatebuf[b * 8 + tid]);
        for (int k = tid; k < Hn; k += THREADS) {
            const float rr = hsigf(xrow[512 + k] + aloadf(&G1buf[(size_t)b * NU + 512 + k]));
            rh_s[k] = rr * h_s[k];
        }
        __syncthreads();

        if (tid < 128) {
            const int gq = tid % 32, kq = tid / 32;
            const int j0 = 128 * s + 4 * gq;
            const float* wp = Umat + (size_t)(kq * 128) * N3 + 1024 + j0;
            float4 acc = {0.f, 0.f, 0.f, 0.f};
#pragma unroll 8
            for (int k = 0; k < 128; ++k) {
                const float4 w = *(const float4*)(wp + (size_t)k * N3);
                const float r_ = rh_s[kq * 128 + k];
                acc.x = fmaf(w.x, r_, acc.x); acc.y = fmaf(w.y, r_, acc.y);
                acc.z = fmaf(w.z, r_, acc.z); acc.w = fmaf(w.w, r_, acc.w);
            }
            *(float4*)&red_s[kq][4 * gq] = acc;
        }
        __syncthreads();

        if (tid < 128) {
            const int j = 128 * s + tid;
            const float dot = red_s[0][tid] + red_s[1][tid] + red_s[2][tid] + red_s[3][tid];
            const float z = hsigf(xrow[j] + aloadf(&G1buf[(size_t)b * NU + j]));
            const float hp = h_s[j];
            const float th = tanhf(xrow[1024 + j] + dot);
            const float hc = z * hp + (1.f - z) * th;
            const float xt = o_pix[(((size_t)b * DEP + d) * Tn + t) * Hn + j];
            const float both = gate_s[0], h_only = gate_s[1],
                        x_only = gate_s[2], dmpv = gate_s[3];
            float hv = (both > 0.f) ? hc : 0.f;
            if (h_only > 0.f) hv = hp;
            if (x_only > 0.f) hv = xt;
            if (!(dmpv > 0.f)) hv = hp;
            astoref(&hbuf[((size_t)(par ^ 1) * Bn + b) * Hn + j], hv);
            if (d < DEP - 1) o_pix[(((size_t)b * DEP + d + 1) * Tn + t) * Hn + j] = hv;
            if (t > 0)       o_pih[(((size_t)b * DEP + d) * Tn + t) * Hn + j] = hv;
            if (d == DEP - 1 && t == Tn - 1) o_out[(size_t)b * Hn + j] = hv;
        }

        // ---- sync2: h(t) complete
        __syncthreads();
        if (tid == 0) {
            __hip_atomic_fetch_add(&arr2[b], 1u, __ATOMIC_RELAXED, __HIP_MEMORY_SCOPE_AGENT);
            while (__hip_atomic_load(&arr2[b], __ATOMIC_RELAXED, __HIP_MEMORY_SCOPE_AGENT) < tgt)
                __builtin_amdgcn_s_sleep(1);
        }
        __syncthreads();
    }
}

// ---------------------------------------------------------------------------
extern "C" void kernel_launch(void* const* d_in, const int* in_sizes, int n_in,
                              void* d_out, int out_size, void* d_ws, size_t ws_size,
                              hipStream_t stream) {
    const float* x     = (const float*)d_in[0];
    const float* mask  = (const float*)d_in[1];
    const float* W_emb = (const float*)d_in[3];
    const float* b_emb = (const float*)d_in[4];
    const float* W     = (const float*)d_in[5];
    const float* U     = (const float*)d_in[6];
    const float* bb    = (const float*)d_in[7];
    const float* Wa1   = (const float*)d_in[8];
    const float* Ua1   = (const float*)d_in[9];
    const float* ba1   = (const float*)d_in[10];
    const float* W2    = (const float*)d_in[11];
    const float* b2    = (const float*)d_in[12];

    float* out = (float*)d_out;
    float* o_out = out;
    float* o_act = out + (size_t)Bn * Hn;
    float* o_ac  = o_act + (size_t)Bn * DEP * Tn;
    float* o_pix = o_ac + (size_t)Bn * DEP * Tn;
    float* o_pih = o_pix + (size_t)Bn * DEP * Tn * Hn;
    float* o_pol = o_pih + (size_t)Bn * DEP * Tn * Hn;

    float* ws      = (float*)d_ws;
    float* seos    = ws;                                  // 16384
    float* dmh     = seos + Tn * Bn;                      // 5*16384
    float* acth    = dmh + (DEP + 1) * Tn * Bn;           // 16384
    float* hbuf    = acth + Tn * Bn;                      // 2*B*H = 65536
    float* G1buf   = hbuf + 2 * Bn * Hn;                  // B*NU = 73728
    float* gatebuf = G1buf + (size_t)Bn * NU;             // 512
    unsigned int* flags = (unsigned int*)(gatebuf + Bn * 8);  // 128 u32
    float* Wc      = gatebuf + Bn * 8 + 128;              // H*NC
    float* bc      = Wc + (size_t)Hn * NC;                // NC
    float* Uc      = bc + NC;                             // H*NU
    float* XWA     = Uc + (size_t)Hn * NU;                // 64*B*NC

    pack_w_k<<<(Hn * NC + 255) / 256, 256, 0, stream>>>(W, Wa1, Wc);
    pack_u_k<<<(Hn * NU + 255) / 256, 256, 0, stream>>>(U, Ua1, Uc);
    init_misc_k<<<(Bn * DEP * Hn + 255) / 256, 256, 0, stream>>>(
        bb, ba1, bc, mask, seos, dmh, o_pih, flags);

    // emb: pix[:,0] = x @ W_emb + b_emb
    gemm64_k<<<dim3(Tn, Hn / 64), 256, 0, stream>>>(
        x, 0L, (long)DIN, (long)Tn * DIN, W_emb, Hn, b_emb,
        o_pix, 0L, (long)Hn, (long)DEP * Tn * Hn, DIN);

    for (int d = 0; d < DEP; ++d) {
        for (int c = 0; c < 4; ++c) {
            gemm64_k<<<dim3(64, NC / 64), 256, 0, stream>>>(
                o_pix, (long)(d * Tn + c * 64) * Hn, (long)Hn, (long)DEP * Tn * Hn,
                Wc, NC, bc, XWA, 0L, (long)Bn * NC, (long)NC, Hn);
            scan_chunk_k<<<dim3(Bn, 4), THREADS, 0, stream>>>(
                XWA, Uc, U, W2, b2, hbuf, G1buf, gatebuf, flags,
                seos, dmh, acth, o_act, o_ac, o_pol, o_pix, o_pih, o_out, d, c);
        }
    }
}